// Round 6
// baseline (196.174 us; speedup 1.0000x reference)
//
#include <hip/hip_runtime.h>

#define NS 65536      // B*H*W samples
#define D 64          // embed dim
#define K 1024        // codebook size
#define NEL 4194304   // NS*D

// ---------------------------------------------------------------------------
// Prep: transpose codebook [D,K] -> [K,D] (contiguous 256B rows), compute
// ||m_k||^2, zero the loss accumulator.
// ---------------------------------------------------------------------------
__global__ __launch_bounds__(256) void vq_prep(
    const float* __restrict__ cm,   // [D,K]
    float* __restrict__ ct,         // [K,D]
    float* __restrict__ cnorm,      // [K]
    double* __restrict__ acc)
{
    const int k = blockIdx.x * 256 + threadIdx.x;   // 4 blocks x 256 = 1024
    if (k == 0) *acc = 0.0;
    float vals[D];
    float n = 0.f;
#pragma unroll
    for (int d = 0; d < D; ++d) {
        float v = cm[d * K + k];    // coalesced across k
        vals[d] = v;
        n = fmaf(v, v, n);
    }
    cnorm[k] = n;
    float4* dst = (float4*)(ct + (size_t)k * D);
#pragma unroll
    for (int j = 0; j < D / 4; ++j)
        dst[j] = make_float4(vals[4*j], vals[4*j+1], vals[4*j+2], vals[4*j+3]);
}

// ---------------------------------------------------------------------------
// Main: register-tiled VALU GEMM. 1024 blocks x 256 threads.
// Block = 64 samples x 1024 codes (4 tiles of 256). Thread = 8 samples x 8
// codes (64 fp32 accumulators).
// R5 change vs R4: x-fragments hoisted out of the h-loop — all 4 dims x 8
// samples loaded once per dc (8 ds_read_b128 into 32 VGPRs) and reused by
// both mf halves. Halves the LDS pipe load (196k -> 98k cyc/CU), which had
// become the largest per-CU pipe consumer (> FMA's 131k).
// ---------------------------------------------------------------------------
__global__ __launch_bounds__(256, 3) void vq_main(
    const float* __restrict__ xin,    // [NS,D]
    const float* __restrict__ ct,     // [K,D]
    const float* __restrict__ cnorm,  // [K]
    float* __restrict__ outq,         // [NS,D]
    float* __restrict__ outidx,      // [NS] (indices as float)
    double* __restrict__ acc_g)
{
    // Region A (16 KB): x_lds[4096] during GEMM; after a barrier, reused as
    // sbv[32][64] (8 KB) + siv[32][64] (8 KB); then first 1 KB as red[256].
    __shared__ float smemA[4096];
    __shared__ float cn_lds[1024];    // 4 KB
    __shared__ int   widx[64];

    float* x_lds = smemA;                    // [d][s]
    float* sbv   = smemA;                    // [32][64]
    int*   siv   = (int*)(smemA + 2048);     // [32][64]
    float* red   = smemA;                    // [256]

    const int tx = threadIdx.x;
    const int sg = tx & 7;      // sample octet 0..7  (8 samples each)
    const int kg = tx >> 3;     // code lane 0..31
    const int S0 = blockIdx.x * 64;

    // ---- stage x transposed into LDS [d][s]; stage cnorm ----
    {
        const int s  = tx >> 2;          // 0..63
        const int d0 = (tx & 3) * 16;    // 0/16/32/48
        const float* gp = xin + (size_t)(S0 + s) * D + d0;
        float4 v[4];
#pragma unroll
        for (int q = 0; q < 4; ++q) v[q] = ((const float4*)gp)[q];
#pragma unroll
        for (int q = 0; q < 4; ++q) {
            x_lds[(d0 + 4*q + 0) * 64 + s] = v[q].x;
            x_lds[(d0 + 4*q + 1) * 64 + s] = v[q].y;
            x_lds[(d0 + 4*q + 2) * 64 + s] = v[q].z;
            x_lds[(d0 + 4*q + 3) * 64 + s] = v[q].w;
        }
#pragma unroll
        for (int q = 0; q < 4; ++q) cn_lds[q*256 + tx] = cnorm[q*256 + tx];
    }
    __syncthreads();

    float best[8];
    int   bidx[8];
#pragma unroll
    for (int i = 0; i < 8; ++i) { best[i] = 3.4e38f; bidx[i] = 0; }

    // ---- 4 tiles of 256 codes; thread's codes k = t*256 + j*32 + kg ----
    for (int t = 0; t < 4; ++t) {
        float acc[8][8];
#pragma unroll
        for (int i = 0; i < 8; ++i)
#pragma unroll
            for (int j = 0; j < 8; ++j) acc[i][j] = 0.f;

        const float* mbase = ct + (size_t)(t*256 + kg) * D;

        for (int dc = 0; dc < 16; ++dc) {       // 16 chunks of 4 dims
            // hoisted x: 4 dims x 8 samples once per dc (8 ds_read_b128)
            float4 xs[8];
#pragma unroll
            for (int dd = 0; dd < 4; ++dd) {
                const float* xr = x_lds + (dc*4 + dd)*64 + sg*8;
                xs[2*dd]     = *(const float4*)(xr);
                xs[2*dd + 1] = *(const float4*)(xr + 4);
            }
#pragma unroll
            for (int h = 0; h < 2; ++h) {       // two j-halves of 4 codes
                float4 mf[4];
#pragma unroll
                for (int j = 0; j < 4; ++j)
                    mf[j] = *(const float4*)(mbase + (h*4 + j)*32*D + dc*4);
#pragma unroll
                for (int dd = 0; dd < 4; ++dd) {
                    const float4 xa = xs[2*dd];
                    const float4 xb = xs[2*dd + 1];
#pragma unroll
                    for (int j = 0; j < 4; ++j) {
                        const float ms = (dd == 0) ? mf[j].x :
                                         (dd == 1) ? mf[j].y :
                                         (dd == 2) ? mf[j].z : mf[j].w;
                        const int jj = h*4 + j;
                        acc[0][jj] = fmaf(xa.x, ms, acc[0][jj]);
                        acc[1][jj] = fmaf(xa.y, ms, acc[1][jj]);
                        acc[2][jj] = fmaf(xa.z, ms, acc[2][jj]);
                        acc[3][jj] = fmaf(xa.w, ms, acc[3][jj]);
                        acc[4][jj] = fmaf(xb.x, ms, acc[4][jj]);
                        acc[5][jj] = fmaf(xb.y, ms, acc[5][jj]);
                        acc[6][jj] = fmaf(xb.z, ms, acc[6][jj]);
                        acc[7][jj] = fmaf(xb.w, ms, acc[7][jj]);
                    }
                }
            }
        }
        // distances + running argmin (j ascending => k ascending, strict <)
#pragma unroll
        for (int j = 0; j < 8; ++j) {
            const int k = t*256 + j*32 + kg;
            const float cnv = cn_lds[k];
#pragma unroll
            for (int i = 0; i < 8; ++i) {
                float dist = fmaf(-2.f, acc[i][j], cnv);
                if (dist < best[i]) { best[i] = dist; bidx[i] = k; }
            }
        }
    }

    // ---- combine across the 32 kg-threads per sample ----
    __syncthreads();   // x_lds dead everywhere before sbv/siv overwrite it
#pragma unroll
    for (int i = 0; i < 8; ++i) {
        sbv[kg*64 + sg*8 + i] = best[i];
        siv[kg*64 + sg*8 + i] = bidx[i];
    }
    __syncthreads();
    if (tx < 64) {
        float b = sbv[tx];
        int   w = siv[tx];
#pragma unroll
        for (int p = 1; p < 32; ++p) {
            float bp = sbv[p*64 + tx];
            if (bp < b) { b = bp; w = siv[p*64 + tx]; }
        }
        widx[tx] = w;
    }
    __syncthreads();   // after this, sbv/siv dead -> red may reuse region

    // ---- gather + STE output + loss partial ----
    const int sl = tx >> 2;                 // local sample 0..63
    const int d0 = (tx & 3) * 16;           // dim offset
    const int gs = blockIdx.x * 64 + sl;
    const int w  = widx[sl];
    const float* mq = ct + ((size_t)w << 6) + d0;
    const float* xr = xin + (size_t)gs * D + d0;
    float*       oq = outq + (size_t)gs * D + d0;
    float psum = 0.f;
#pragma unroll
    for (int j = 0; j < 16; j += 4) {
        float4 q  = *(const float4*)(mq + j);
        float4 xv = *(const float4*)(xr + j);
        float4 o;
        float dx = q.x - xv.x, dy = q.y - xv.y, dz = q.z - xv.z, dw = q.w - xv.w;
        o.x = xv.x + dx; o.y = xv.y + dy; o.z = xv.z + dz; o.w = xv.w + dw;
        *(float4*)(oq + j) = o;
        psum = fmaf(dx, dx, psum);
        psum = fmaf(dy, dy, psum);
        psum = fmaf(dz, dz, psum);
        psum = fmaf(dw, dw, psum);
    }

    if (tx < 64)
        outidx[blockIdx.x * 64 + tx] = (float)widx[tx];

    red[tx] = psum;
    __syncthreads();
    for (int st = 128; st > 0; st >>= 1) {
        if (tx < st) red[tx] += red[tx + st];
        __syncthreads();
    }
    if (tx == 0) atomicAdd(acc_g, (double)red[0]);
}

// ---------------------------------------------------------------------------
// Finalize: loss = m + 0.25*m where m = mean((q-x)^2)
// ---------------------------------------------------------------------------
__global__ void vq_finalize(const double* __restrict__ acc,
                            float* __restrict__ loss_out)
{
    float m = (float)(*acc / (double)NEL);
    *loss_out = m + 0.25f * m;
}

extern "C" void kernel_launch(void* const* d_in, const int* in_sizes, int n_in,
                              void* d_out, int out_size, void* d_ws, size_t ws_size,
                              hipStream_t stream) {
    const float* xin = (const float*)d_in[0];   // [16,64,64,64] fp32
    const float* cm  = (const float*)d_in[1];   // [64,1024] fp32

    float* out     = (float*)d_out;
    float* outq    = out;                 // 4194304 floats
    float* outidx  = out + NEL;           // 65536 floats (indices)
    float* outloss = out + NEL + NS;      // 1 float

    float*  ct    = (float*)d_ws;         // 65536 floats = 256 KB
    float*  cnorm = ct + (size_t)K * D;   // 1024 floats
    double* acc   = (double*)(cnorm + K); // 8B-aligned

    vq_prep<<<4, 256, 0, stream>>>(cm, ct, cnorm, acc);
    vq_main<<<1024, 256, 0, stream>>>(xin, ct, cnorm, outq, outidx, acc);
    vq_finalize<<<1, 1, 0, stream>>>(acc, outloss);
}